// Round 17
// baseline (16.232 us; speedup 1.0000x reference)
//
#include <hip/hip_runtime.h>

// MorphTEmbedding R17: R11 structure, 2 tokens/wave, FULL occupancy single
// generation: 8192 waves = 2048 blocks x 4 waves = 8 blocks/CU = 32 waves/CU.
// (R13's TPW=4 ran half-occupancy; R3's TPW=2 lacked nt stores + had in-loop
// global loads.) Token-0 stores issue before token-1 LN completes, spreading
// store issue. __launch_bounds__(256,8) caps VGPR<=64 to hold 8 waves/SIMD.

#define RANK      8
#define NUM_MORPH 10000
#define EMB       512
#define LN_EPS    1e-5f
#define WPB       4
#define RSTRIDE   80000

typedef float f32x4 __attribute__((ext_vector_type(4)));

template <int CTRL>
__device__ __forceinline__ float dpp_add(float v) {
    return v + __int_as_float(__builtin_amdgcn_update_dpp(
        __float_as_int(v), __float_as_int(v), CTRL, 0xf, 0xf, false));
}
__device__ __forceinline__ float rdlane(float v, int l) {
    return __int_as_float(__builtin_amdgcn_readlane(__float_as_int(v), l));
}

__global__ __launch_bounds__(256, 8) void morph_emb_kernel(
    const int* __restrict__ x,       // [n_tok]
    const int* __restrict__ co,      // [NUM_SURF, 3]
    const float* __restrict__ W,     // [RANK, NUM_MORPH, 8]
    const float* __restrict__ lns,   // [512]
    const float* __restrict__ lnb,   // [512]
    float* __restrict__ out,         // [n_tok, 512]
    int n_tok) {
    const int lane = threadIdx.x & 63;
    const int wid  = blockIdx.x * WPB + (threadIdx.x >> 6);
    const int t0   = wid * 2;
    const int tA   = (t0     < n_tok) ? t0     : (n_tok - 1);
    const int tB   = (t0 + 1 < n_tok) ? t0 + 1 : (n_tok - 1);

    // uniform index chains for both tokens (issued together -> MLP)
    const int sA  = x[tA];
    const int sB  = x[tB];
    const int mA0 = co[sA * 3 + 0], mA1 = co[sA * 3 + 1], mA2 = co[sA * 3 + 2];
    const int mB0 = co[sB * 3 + 0], mB1 = co[sB * 3 + 1], mB2 = co[sB * 3 + 2];

    const int ia = lane >> 3;
    const int ib = lane & 7;

    // gathers for both tokens, all issued before consumption
    const float cA =
        W[(size_t)ia * RSTRIDE + (size_t)mA2 * 8 + ib];
    const float cB =
        W[(size_t)ia * RSTRIDE + (size_t)mB2 * 8 + ib];

    const float* paA = W + (size_t)mA0 * 8 + ia;
    const float* pbA = W + (size_t)mA1 * 8 + ib;
    const float* paB = W + (size_t)mB0 * 8 + ia;
    const float* pbB = W + (size_t)mB1 * 8 + ib;

    float pA[RANK], pB[RANK];
#pragma unroll
    for (int r = 0; r < RANK; ++r) {
        pA[r] = paA[r * RSTRIDE] * pbA[r * RSTRIDE];
        pB[r] = paB[r * RSTRIDE] * pbB[r * RSTRIDE];
    }

    // LN params: e = lane*8 -> 4 dwordx4 loads (shared by both tokens)
    const int e = lane << 3;
    const f32x4 g0 = *reinterpret_cast<const f32x4*>(lns + e);
    const f32x4 g1 = *reinterpret_cast<const f32x4*>(lns + e + 4);
    const f32x4 b0 = *reinterpret_cast<const f32x4*>(lnb + e);
    const f32x4 b1 = *reinterpret_cast<const f32x4*>(lnb + e + 4);

    // ---- token A compute + LN + store (drains early) ----
    float accA[8] = {0.f, 0.f, 0.f, 0.f, 0.f, 0.f, 0.f, 0.f};
#pragma unroll
    for (int r = 0; r < RANK; ++r) {
#pragma unroll
        for (int j = 0; j < 8; ++j)
            accA[j] = fmaf(pA[r], rdlane(cA, r * 8 + j), accA[j]);
    }
    float smA = 0.f, sqA = 0.f;
#pragma unroll
    for (int j = 0; j < 8; ++j) { smA += accA[j]; sqA += accA[j] * accA[j]; }
    smA = dpp_add<0xB1>(smA);  sqA = dpp_add<0xB1>(sqA);
    smA = dpp_add<0x4E>(smA);  sqA = dpp_add<0x4E>(sqA);
    smA = dpp_add<0x141>(smA); sqA = dpp_add<0x141>(sqA);
    smA = dpp_add<0x140>(smA); sqA = dpp_add<0x140>(sqA);
    {
        const float ts = (rdlane(smA, 0) + rdlane(smA, 16)) +
                         (rdlane(smA, 32) + rdlane(smA, 48));
        const float tq = (rdlane(sqA, 0) + rdlane(sqA, 16)) +
                         (rdlane(sqA, 32) + rdlane(sqA, 48));
        const float mu = ts * (1.0f / EMB);
        const float rs = rsqrtf(tq * (1.0f / EMB) - mu * mu + LN_EPS);
        if (t0 < n_tok) {
            f32x4 o0, o1;
            o0[0] = (accA[0] - mu) * rs * g0[0] + b0[0];
            o0[1] = (accA[1] - mu) * rs * g0[1] + b0[1];
            o0[2] = (accA[2] - mu) * rs * g0[2] + b0[2];
            o0[3] = (accA[3] - mu) * rs * g0[3] + b0[3];
            o1[0] = (accA[4] - mu) * rs * g1[0] + b1[0];
            o1[1] = (accA[5] - mu) * rs * g1[1] + b1[1];
            o1[2] = (accA[6] - mu) * rs * g1[2] + b1[2];
            o1[3] = (accA[7] - mu) * rs * g1[3] + b1[3];
            f32x4* op = reinterpret_cast<f32x4*>(out + (size_t)t0 * EMB + e);
            __builtin_nontemporal_store(o0, op);
            __builtin_nontemporal_store(o1, op + 1);
        }
    }

    // ---- token B compute + LN + store ----
    float accB[8] = {0.f, 0.f, 0.f, 0.f, 0.f, 0.f, 0.f, 0.f};
#pragma unroll
    for (int r = 0; r < RANK; ++r) {
#pragma unroll
        for (int j = 0; j < 8; ++j)
            accB[j] = fmaf(pB[r], rdlane(cB, r * 8 + j), accB[j]);
    }
    float smB = 0.f, sqB = 0.f;
#pragma unroll
    for (int j = 0; j < 8; ++j) { smB += accB[j]; sqB += accB[j] * accB[j]; }
    smB = dpp_add<0xB1>(smB);  sqB = dpp_add<0xB1>(sqB);
    smB = dpp_add<0x4E>(smB);  sqB = dpp_add<0x4E>(sqB);
    smB = dpp_add<0x141>(smB); sqB = dpp_add<0x141>(sqB);
    smB = dpp_add<0x140>(smB); sqB = dpp_add<0x140>(sqB);
    {
        const float ts = (rdlane(smB, 0) + rdlane(smB, 16)) +
                         (rdlane(smB, 32) + rdlane(smB, 48));
        const float tq = (rdlane(sqB, 0) + rdlane(sqB, 16)) +
                         (rdlane(sqB, 32) + rdlane(sqB, 48));
        const float mu = ts * (1.0f / EMB);
        const float rs = rsqrtf(tq * (1.0f / EMB) - mu * mu + LN_EPS);
        if (t0 + 1 < n_tok) {
            f32x4 o0, o1;
            o0[0] = (accB[0] - mu) * rs * g0[0] + b0[0];
            o0[1] = (accB[1] - mu) * rs * g0[1] + b0[1];
            o0[2] = (accB[2] - mu) * rs * g0[2] + b0[2];
            o0[3] = (accB[3] - mu) * rs * g0[3] + b0[3];
            o1[0] = (accB[4] - mu) * rs * g1[0] + b1[0];
            o1[1] = (accB[5] - mu) * rs * g1[1] + b1[1];
            o1[2] = (accB[6] - mu) * rs * g1[2] + b1[2];
            o1[3] = (accB[7] - mu) * rs * g1[3] + b1[3];
            f32x4* op = reinterpret_cast<f32x4*>(out + (size_t)(t0 + 1) * EMB + e);
            __builtin_nontemporal_store(o0, op);
            __builtin_nontemporal_store(o1, op + 1);
        }
    }
}

extern "C" void kernel_launch(void* const* d_in, const int* in_sizes, int n_in,
                              void* d_out, int out_size, void* d_ws, size_t ws_size,
                              hipStream_t stream) {
    const int*   x   = (const int*)d_in[0];
    const int*   co  = (const int*)d_in[1];
    const float* W   = (const float*)d_in[2];
    const float* lns = (const float*)d_in[3];
    const float* lnb = (const float*)d_in[4];
    float*       out = (float*)d_out;

    const int n_tok  = in_sizes[0];                       // 16384
    const int blocks = (n_tok / 2 + WPB - 1) / WPB;       // 2048
    morph_emb_kernel<<<blocks, WPB * 64, 0, stream>>>(x, co, W, lns, lnb, out, n_tok);
}